// Round 13
// baseline (203.066 us; speedup 1.0000x reference)
//
#include <hip/hip_runtime.h>
#include <stdint.h>

typedef _Float16 h2 __attribute__((ext_vector_type(2)));
typedef _Float16 h4 __attribute__((ext_vector_type(4)));
typedef float    f4 __attribute__((ext_vector_type(4)));

static constexpr int CDIM = 32;     // channels
static constexpr int NPIX = 16384;  // H*W = 128*128
static constexpr int SSAM = 1024;   // samples per row
static constexpr int ROWS_PER_BLOCK = 16;   // for the gather kernel

__device__ __forceinline__ uint16_t f2h(float f) {
    union { _Float16 h; uint16_t u; } c;
    c.h = (_Float16)f;
    return c.u;
}

template<int CTRL>
__device__ __forceinline__ float dpp_add(float x) {
    int y = __builtin_amdgcn_mov_dpp(__float_as_int(x), CTRL, 0xF, 0xF, true);
    return x + __int_as_float(y);
}

__device__ __forceinline__ float dot2(h2 a, h2 b, float c) {
    return __builtin_amdgcn_fdot2(a, b, c, false);   // v_dot2_f32_f16
}

// ---------------------------------------------------------------------------
// Kernel 1: layout prep. key/query [B][C][N] f32 -> [B*N][32] f16 rows (64B);
// query pre-scaled by C^-0.5. Also emits seg8 and zeroes segbit (2 words/thr).
// ---------------------------------------------------------------------------
__global__ __launch_bounds__(256)
void prep_kernel(const float* __restrict__ key_f,
                 const float* __restrict__ query_f,
                 const int* __restrict__ seg32,
                 uint8_t* __restrict__ key16,
                 uint8_t* __restrict__ q16,
                 uint8_t* __restrict__ seg8,
                 uint32_t* __restrict__ segbit,
                 int N, int rows, float scale)
{
    int gI = blockIdx.x * 256 + threadIdx.x;
    if (gI >= rows) return;
    segbit[2 * gI]     = 0;
    segbit[2 * gI + 1] = 0;
    seg8[gI] = (uint8_t)seg32[gI];

    int b = gI / N, n = gI - b * N;
    const size_t cb = (size_t)b * CDIM;

    uint32_t kp[16], qp[16];
#pragma unroll
    for (int c = 0; c < CDIM; c += 2) {
        float k0 = key_f[(cb + c) * N + n];
        float k1 = key_f[(cb + c + 1) * N + n];
        float q0 = query_f[(cb + c) * N + n] * scale;
        float q1 = query_f[(cb + c + 1) * N + n] * scale;
        kp[c >> 1] = (uint32_t)f2h(k0) | ((uint32_t)f2h(k1) << 16);
        qp[c >> 1] = (uint32_t)f2h(q0) | ((uint32_t)f2h(q1) << 16);
    }
    uint4* ko = (uint4*)(key16 + ((size_t)gI << 6));
    uint4* qo = (uint4*)(q16 + ((size_t)gI << 6));
#pragma unroll
    for (int j = 0; j < 4; ++j) {
        ko[j] = make_uint4(kp[4*j], kp[4*j+1], kp[4*j+2], kp[4*j+3]);
        qo[j] = make_uint4(qp[4*j], qp[4*j+1], qp[4*j+2], qp[4*j+3]);
    }
}

// ---------------------------------------------------------------------------
// Kernel 1b: segment bitmap. segbit[b][v][512]: bit n set iff seg[b][n]==v.
// ---------------------------------------------------------------------------
__global__ __launch_bounds__(256)
void segbit_build(const int* __restrict__ seg32,
                  uint32_t* __restrict__ segbit,
                  int N, int rows)
{
    int g = blockIdx.x * 256 + threadIdx.x;
    if (g >= rows) return;
    int b = g / N, n = g - b * N;
    int v = seg32[g] & 63;
    atomicOr(&segbit[(((size_t)(b * 64 + v)) << 9) + (n >> 5)], 1u << (n & 31));
}

// ---------------------------------------------------------------------------
// Kernel A: dense local logits for s < 512 (the deterministic 25x25 local
// window prefix of sample_inds, per the reference's _local_indices).
// One block per 8x8 query tile. Clamped 32x32 key window staged strip-by-
// strip (8 window rows = 256 slots, 80B stride); per strip a 64x256x32 GEMM
// via 2x v_mfma_f32_16x16x16_f16 (known CDNA fragment layout) into wave-
// private LDS; selection writes logits + accumulates (Z,T,SL) partials.
// Clamping handled wholly at staging: slot(i,j) = key[clamp(y0-12+i)][...],
// and local sample s of query (qy,qx) maps to i=qy+s/25, j=qx+s%25.
// ---------------------------------------------------------------------------
__global__ __launch_bounds__(256)
void dense_local(const uint8_t* __restrict__ key16,
                 const uint8_t* __restrict__ q16,
                 const uint8_t* __restrict__ seg8,
                 float* __restrict__ out,
                 float* __restrict__ zA,
                 float* __restrict__ tA,
                 float* __restrict__ slA)
{
    const int tid  = threadIdx.x;
    const int bid  = blockIdx.x;
    const int b    = bid >> 8;             // 256 tiles per image
    const int t8   = bid & 255;
    const int y0   = (t8 >> 4) << 3;
    const int x0   = (t8 & 15) << 3;
    const int lane = tid & 63;
    const int w    = tid >> 6;

    __shared__ __align__(16) uint8_t kslot[256 * 80];   // 20KB strip keys
    __shared__ __align__(16) float   res[4][16][256];   // 64KB, wave-private
    __shared__ uint8_t wseg[1024];                      // window seg
    __shared__ float   rowacc[4][16][3];                // Z,T,SL per query

    const uint8_t* kb = key16 + ((size_t)b << 20);
    const uint8_t* sb = seg8 + ((size_t)b << 14);
    const int yo = y0 - 12, xo = x0 - 12;               // unclamped origin

    // stage window seg (clamped)
    for (int s = tid; s < 1024; s += 256) {
        int i = s >> 5, j = s & 31;
        int yy = min(max(yo + i, 0), 127);
        int xx = min(max(xo + j, 0), 127);
        wseg[s] = sb[(yy << 7) + xx];
    }
    if (tid < 192) ((float*)rowacc)[tid] = 0.f;

    // A fragments, once: wave w owns queries 16w..16w+15
    const int qsel = (w << 4) + (lane & 15);
    const int qyA  = qsel >> 3, qxA = qsel & 7;
    const size_t qrow = ((size_t)b << 14) + ((size_t)(y0 + qyA) << 7) + (x0 + qxA);
    const int koff = (lane >> 4) << 3;                  // 8*(lane/16) bytes
    const h4 a0 = *(const h4*)(q16 + (qrow << 6) + koff);
    const h4 a1 = *(const h4*)(q16 + (qrow << 6) + 32 + koff);

    __syncthreads();    // wseg + rowacc visible

    for (int t = 0; t < 4; ++t) {
        // stage strip keys (all waves done with previous strip's GEMM)
        for (int s = tid; s < 1024; s += 256) {
            int slot = s >> 2, q = s & 3;
            int i = (t << 3) + (slot >> 5), j = slot & 31;
            int yy = min(max(yo + i, 0), 127);
            int xx = min(max(xo + j, 0), 127);
            *(uint4*)(kslot + slot * 80 + (q << 4)) =
                *(const uint4*)(kb + ((((size_t)(yy << 7)) + xx) << 6) + (q << 4));
        }
        __syncthreads();

        // GEMM: 16 N-tiles of 16 window slots each
#pragma unroll 4
        for (int n = 0; n < 16; ++n) {
            const uint8_t* kr = kslot + ((n << 4) + (lane & 15)) * 80;
            h4 b0 = *(const h4*)(kr + koff);
            h4 b1 = *(const h4*)(kr + 32 + koff);
            f4 acc = {0.f, 0.f, 0.f, 0.f};
            acc = __builtin_amdgcn_mfma_f32_16x16x16f16(a0, b0, acc, 0, 0, 0);
            acc = __builtin_amdgcn_mfma_f32_16x16x16f16(a1, b1, acc, 0, 0, 0);
#pragma unroll
            for (int r = 0; r < 4; ++r)
                res[w][((lane >> 4) << 2) + r][(n << 4) + (lane & 15)] = acc[r];
        }

        // selection: wave's 16 rows, contiguous s-span for this strip
        for (int m = 0; m < 16; ++m) {
            const int q  = (w << 4) + m;
            const int qy = q >> 3, qx = q & 7;
            const int row = (b << 14) + ((y0 + qy) << 7) + (x0 + qx);
            const int segr = (int)wseg[((qy + 12) << 5) + qx + 12]; // = seg[row]
            int sLo = ((t << 3) - qy) * 25; if (sLo < 0) sLo = 0;
            int sHi = ((t << 3) - qy + 8) * 25; if (sHi > 512) sHi = 512;
            float z = 0.f, tc = 0.f, sl = 0.f;
            for (int s = sLo + lane; s < sHi; s += 64) {
                int d25 = (s * 5243) >> 17;          // s/25 (exact for s<512)
                int r25 = s - d25 * 25;              // s%25
                int i  = qy + d25;                   // window row
                int wc = qx + r25;                   // window col
                float v = res[w][m][((i - (t << 3)) << 5) + wc];
                out[((size_t)row << 10) + s] = v;    // coalesced 64-lane run
                z += __expf(v);
                if ((int)wseg[(i << 5) + wc] == segr) { tc += 1.f; sl += v; }
            }
#pragma unroll
            for (int off = 32; off >= 1; off >>= 1) {
                z  += __shfl_xor(z,  off, 64);
                tc += __shfl_xor(tc, off, 64);
                sl += __shfl_xor(sl, off, 64);
            }
            if (lane == 0) {
                rowacc[w][m][0] += z;
                rowacc[w][m][1] += tc;
                rowacc[w][m][2] += sl;
            }
        }
        __syncthreads();    // all waves done before next strip restages kslot
    }

    // write per-row partials
    if (tid < 64) {
        int q = tid, qy = q >> 3, qx = q & 7;
        int row = (b << 14) + ((y0 + qy) << 7) + (x0 + qx);
        zA[row]  = rowacc[q >> 4][q & 15][0];
        tA[row]  = rowacc[q >> 4][q & 15][1];
        slA[row] = rowacc[q >> 4][q & 15][2];
    }
}

// ---------------------------------------------------------------------------
// Kernel B: gathered logits for s in [512,1024) — R9 structure, half depth.
// Persistent 16-row blocks, one barrier/row, segbit targets, closed-form KL
// merged with kernel A's partials.
// ---------------------------------------------------------------------------
__global__ __launch_bounds__(256)
void affinity_rand(const int* __restrict__ inds,
                   const uint8_t* __restrict__ key16,
                   const uint8_t* __restrict__ q16,
                   const int* __restrict__ seg32,
                   const uint32_t* __restrict__ segbit,
                   const float* __restrict__ zA,
                   const float* __restrict__ tA,
                   const float* __restrict__ slA,
                   float* __restrict__ out,
                   float* __restrict__ ws_kl)
{
    const int tid  = threadIdx.x;
    const int row0 = blockIdx.x * ROWS_PER_BLOCK;
    const int b    = row0 >> 14;
    const int lane = tid & 63;
    const int w    = tid >> 6;
    const int g    = lane >> 2;
    const int sub  = lane & 3;

    __shared__ __align__(16) int      idx_lds[2][512];   // 2 x 2KB
    __shared__ __align__(16) uint32_t bm_lds[2][512];    // 2 x 2KB
    __shared__ float red[2][3][4];
    __shared__ float zp[ROWS_PER_BLOCK], tp[ROWS_PER_BLOCK], sp[ROWS_PER_BLOCK];

    const uint32_t* sbase_bm = segbit + ((size_t)(b * 64) << 9);

    // prologue: partials from kernel A + row0 state
    if (tid < ROWS_PER_BLOCK)      zp[tid] = zA[row0 + tid];
    else if (tid < 2*ROWS_PER_BLOCK) tp[tid - ROWS_PER_BLOCK] = tA[row0 + tid - ROWS_PER_BLOCK];
    else if (tid < 3*ROWS_PER_BLOCK) sp[tid - 2*ROWS_PER_BLOCK] = slA[row0 + tid - 2*ROWS_PER_BLOCK];

    ((int2*)idx_lds[0])[tid] =
        ((const int2*)(inds + ((size_t)row0 << 10) + 512))[tid];
    int scur = seg32[row0];
    ((uint2*)bm_lds[0])[tid] =
        ((const uint2*)(sbase_bm + ((size_t)(scur & 63) << 9)))[tid];
    uint4 qcur = *(const uint4*)(q16 + ((size_t)row0 << 6) + (sub << 4));
    __syncthreads();

    const uint8_t* kb = key16 + ((size_t)b << 20);
    const uint32_t subs = (uint32_t)(sub << 4);
    const int sbase = (w << 7) + g;        // local sample (within 512)

    for (int r = 0; r < ROWS_PER_BLOCK; ++r) {
        const int row = row0 + r;
        const int p   = r & 1;
        const int* cur = idx_lds[p];
        const bool hasNext = (r + 1 < ROWS_PER_BLOCK);

        h2 qh0, qh1, qh2, qh3;
        {
            union { uint4 u; h2 h[4]; } qc; qc.u = qcur;
            qh0 = qc.h[0]; qh1 = qc.h[1]; qh2 = qc.h[2]; qh3 = qc.h[3];
        }
        const int seg_n = scur;

        int idxs[8];
#pragma unroll
        for (int i = 0; i < 8; ++i)
            idxs[i] = cur[sbase + (i << 4)];

        uint4 kd[8];
#pragma unroll
        for (int i = 0; i < 8; ++i)
            kd[i] = *(const uint4*)(kb + (((uint32_t)idxs[i] << 6) | subs));

        // latency cover: next-row prefetch + bitmap flags
        int2 pre; uint4 qnext; uint2 pre_bm; int snext;
        if (hasNext) {
            pre    = ((const int2*)(inds + ((size_t)(row + 1) << 10) + 512))[tid];
            qnext  = *(const uint4*)(q16 + ((size_t)(row + 1) << 6) + (sub << 4));
            snext  = seg32[row + 1];
            pre_bm = ((const uint2*)(sbase_bm + ((size_t)(snext & 63) << 9)))[tid];
        }
        int tfm = 0;
#pragma unroll
        for (int j = 0; j < 2; ++j) {
            int idx = cur[sbase + (((j << 2) | sub) << 4)];
            if ((bm_lds[p][idx >> 5] >> (idx & 31)) & 1u) tfm |= 1 << j;
        }

        float lg0 = 0.f, lg1 = 0.f;
#pragma unroll
        for (int i = 0; i < 8; ++i) {
            union { uint4 u; h2 h[4]; } kc; kc.u = kd[i];
            float acc = dot2(kc.h[0], qh0, 0.f);
            acc = dot2(kc.h[1], qh1, acc);
            acc = dot2(kc.h[2], qh2, acc);
            acc = dot2(kc.h[3], qh3, acc);
            acc = dpp_add<0xB1>(acc);
            acc = dpp_add<0x4E>(acc);
            if (sub == (i & 3)) {
                if ((i >> 2) == 0) lg0 = acc;
                else               lg1 = acc;
            }
        }

        // owner-lane coalesced stores (samples 512 + sbase-pattern)
        const size_t rowbase = (size_t)row << 10;
        float* op = out + rowbase + 512 + (w << 7) + (sub << 4) + g;
        op[0]  = lg0;
        op[64] = lg1;

        float z  = __expf(lg0) + __expf(lg1);
        float tc = (float)__popc((unsigned)tfm);
        float sl = 0.f;
        sl += (tfm & 1) ? lg0 : 0.f;
        sl += (tfm & 2) ? lg1 : 0.f;
#pragma unroll
        for (int off = 32; off >= 1; off >>= 1) {
            z  += __shfl_xor(z,  off, 64);
            tc += __shfl_xor(tc, off, 64);
            sl += __shfl_xor(sl, off, 64);
        }
        if (lane == 0) {
            red[p][0][w] = z;
            red[p][1][w] = tc;
            red[p][2][w] = sl;
        }

        if (hasNext) {
            ((int2*)idx_lds[p ^ 1])[tid] = pre;
            ((uint2*)bm_lds[p ^ 1])[tid] = pre_bm;
            qcur = qnext;
            scur = snext;
        }
        __syncthreads();                   // the one barrier per row

        if (tid == 0) {
            if (seg_n != 0) {
                const float Z  = zp[r] + (red[p][0][0] + red[p][0][1]) + (red[p][0][2] + red[p][0][3]);
                const float T  = tp[r] + (red[p][1][0] + red[p][1][1]) + (red[p][1][2] + red[p][1][3]);
                const float SL = sp[r] + (red[p][2][0] + red[p][2][1]) + (red[p][2][2] + red[p][2][3]);
                // closed-form KL; T >= 1 (center sample matches itself)
                ws_kl[row] = -__logf(T) - SL / T + __logf(Z);
            } else {
                ws_kl[row] = 0.f;
            }
        }
    }
}

// ---------------------------------------------------------------------------
// Fallback (generic shapes / tiny ws): per-thread gather from native layout.
// ---------------------------------------------------------------------------
__global__ __launch_bounds__(256)
void affinity_fallback(const float* __restrict__ key_f,
                       const float* __restrict__ query_f,
                       const int*   __restrict__ seg32,
                       const int*   __restrict__ inds,
                       float* __restrict__ out,
                       float* __restrict__ ws_kl,
                       int N, int S, float scale)
{
    const int bid = blockIdx.x;
    const int tid = threadIdx.x;
    const int b   = bid / N;

    __shared__ float q_lds[CDIM];
    __shared__ float redA[4], redB[4], redC[4];

    if (tid < CDIM) {
        int n = bid - b * N;
        q_lds[tid] = query_f[((size_t)(b * CDIM + tid)) * N + n];
    }
    const int seg_n = seg32[bid];
    __syncthreads();

    float q[CDIM];
#pragma unroll
    for (int c = 0; c < CDIM; ++c) q[c] = q_lds[c];

    const size_t rowbase = (size_t)bid * S;
    const int4 iv = ((const int4*)(inds + rowbase))[tid];
    const int idxv[4] = {iv.x, iv.y, iv.z, iv.w};

    float lg[4];
    int   tf[4];
#pragma unroll
    for (int k = 0; k < 4; ++k) {
        int idx = idxv[k];
        tf[k] = (seg32[b * N + idx] == seg_n) ? 1 : 0;
        float acc = 0.f;
#pragma unroll
        for (int c = 0; c < CDIM; ++c)
            acc = fmaf(key_f[((size_t)(b * CDIM + c)) * N + idx], q[c], acc);
        lg[k] = acc * scale;
    }
    ((float4*)(out + rowbase))[tid] = make_float4(lg[0], lg[1], lg[2], lg[3]);

    const int lane = tid & 63, wv = tid >> 6;
    float m = fmaxf(fmaxf(lg[0], lg[1]), fmaxf(lg[2], lg[3]));
#pragma unroll
    for (int off = 32; off >= 1; off >>= 1)
        m = fmaxf(m, __shfl_xor(m, off, 64));
    if (lane == 0) redA[wv] = m;
    __syncthreads();
    m = fmaxf(fmaxf(redA[0], redA[1]), fmaxf(redA[2], redA[3]));

    float e[4], z = 0.f, tcnt = 0.f;
#pragma unroll
    for (int k = 0; k < 4; ++k) {
        e[k] = expf(lg[k] - m);
        z += e[k];
        tcnt += (float)tf[k];
    }
#pragma unroll
    for (int off = 32; off >= 1; off >>= 1) {
        z    += __shfl_xor(z, off, 64);
        tcnt += __shfl_xor(tcnt, off, 64);
    }
    if (lane == 0) { redB[wv] = z; redC[wv] = tcnt; }
    __syncthreads();
    const float Z = redB[0] + redB[1] + redB[2] + redB[3];
    const float T = redC[0] + redC[1] + redC[2] + redC[3];

    float kl = 0.f;
    if (seg_n != 0) {
        const float invZ = 1.f / (Z + 1e-9f);
        const float invT = 1.f / (T + 1e-9f);
        const float nlT  = -logf(T + 1e-9f);
#pragma unroll
        for (int k = 0; k < 4; ++k) {
            if (tf[k]) {
                float p = e[k] * invZ;
                float yp = logf(fmaxf(p, 1e-8f));
                kl += invT * (nlT - yp);
            }
        }
    }
#pragma unroll
    for (int off = 32; off >= 1; off >>= 1)
        kl += __shfl_xor(kl, off, 64);
    if (lane == 0) redA[wv] = kl;
    __syncthreads();
    if (tid == 0)
        ws_kl[bid] = redA[0] + redA[1] + redA[2] + redA[3];
}

// ---------------------------------------------------------------------------
// Kernel 3: deterministic single-block loss reduction (1024 threads).
// ---------------------------------------------------------------------------
__global__ __launch_bounds__(1024)
void loss_reduce(const float* __restrict__ ws_kl,
                 const int* __restrict__ seg32,
                 float* __restrict__ out_loss, int rows)
{
    const int tid = threadIdx.x;
    float s = 0.f, c = 0.f;
    for (int i = tid; i < rows; i += 1024) {
        s += ws_kl[i];
        c += (seg32[i] != 0) ? 1.f : 0.f;
    }
#pragma unroll
    for (int off = 32; off >= 1; off >>= 1) {
        s += __shfl_xor(s, off, 64);
        c += __shfl_xor(c, off, 64);
    }
    __shared__ float sA[16], sB[16];
    const int lane = tid & 63, wv = tid >> 6;
    if (lane == 0) { sA[wv] = s; sB[wv] = c; }
    __syncthreads();
    if (tid == 0) {
        float ts = 0.f, tc = 0.f;
#pragma unroll
        for (int k = 0; k < 16; ++k) { ts += sA[k]; tc += sB[k]; }
        out_loss[0] = ts / (tc + 1e-9f);
    }
}

// ---------------------------------------------------------------------------
extern "C" void kernel_launch(void* const* d_in, const int* in_sizes, int n_in,
                              void* d_out, int out_size, void* d_ws, size_t ws_size,
                              hipStream_t stream)
{
    const float* key_f   = (const float*)d_in[0];
    const float* query_f = (const float*)d_in[1];
    const int*   seg32   = (const int*)d_in[2];
    const int*   inds    = (const int*)d_in[3];
    float* out = (float*)d_out;

    const int N    = NPIX;
    const int rows = in_sizes[2];            // B*N
    const int S    = in_sizes[3] / rows;     // 1024
    const float scale = (float)(1.0 / sqrt((double)CDIM));
    const int B    = rows / N;

    // ws: key16 | q16 | seg8 | segbit | zA | tA | slA | kl
    const size_t off_q16 = (size_t)rows * 64;
    const size_t off_s8  = off_q16 + (size_t)rows * 64;
    const size_t off_sb  = (off_s8 + (size_t)rows + 255) & ~(size_t)255;
    const size_t sb_words = (size_t)B * 64 * 512;     // == 2*rows
    const size_t off_zA  = (off_sb + sb_words * 4 + 255) & ~(size_t)255;
    const size_t off_tA  = off_zA + (size_t)rows * 4;
    const size_t off_slA = off_tA + (size_t)rows * 4;
    const size_t off_kl  = off_slA + (size_t)rows * 4;
    const size_t need    = off_kl + (size_t)rows * 4;

    uint8_t* wsb = (uint8_t*)d_ws;
    const bool geom_ok = (S == SSAM) && (rows % N == 0) &&
                         (rows % ROWS_PER_BLOCK == 0);

    if (ws_size >= need && geom_ok) {
        uint8_t*  key16  = wsb;
        uint8_t*  q16    = wsb + off_q16;
        uint8_t*  seg8   = wsb + off_s8;
        uint32_t* segbit = (uint32_t*)(wsb + off_sb);
        float*    zA     = (float*)(wsb + off_zA);
        float*    tA     = (float*)(wsb + off_tA);
        float*    slA    = (float*)(wsb + off_slA);
        float*    wskl   = (float*)(wsb + off_kl);

        prep_kernel<<<(rows + 255) / 256, 256, 0, stream>>>(
            key_f, query_f, seg32, key16, q16, seg8, segbit, N, rows, scale);
        segbit_build<<<(rows + 255) / 256, 256, 0, stream>>>(
            seg32, segbit, N, rows);
        dense_local<<<B * 256, 256, 0, stream>>>(
            key16, q16, seg8, out, zA, tA, slA);
        affinity_rand<<<rows / ROWS_PER_BLOCK, 256, 0, stream>>>(
            inds, key16, q16, seg32, segbit, zA, tA, slA, out, wskl);
        loss_reduce<<<1, 1024, 0, stream>>>(wskl, seg32, out + (size_t)rows * S, rows);
    } else {
        float* wskl = (float*)d_ws;
        affinity_fallback<<<rows, 256, 0, stream>>>(
            key_f, query_f, seg32, inds, out, wskl, N, S, scale);
        loss_reduce<<<1, 1024, 0, stream>>>(wskl, seg32, out + (size_t)rows * S, rows);
    }
}

// Round 14
// 165.643 us; speedup vs baseline: 1.2259x; 1.2259x over previous
//
#include <hip/hip_runtime.h>
#include <stdint.h>

typedef _Float16 h2 __attribute__((ext_vector_type(2)));
typedef _Float16 h4 __attribute__((ext_vector_type(4)));
typedef float    f4 __attribute__((ext_vector_type(4)));

static constexpr int CDIM = 32;     // channels
static constexpr int NPIX = 16384;  // H*W = 128*128
static constexpr int SSAM = 1024;   // samples per row
static constexpr int NLOC = 625;    // 25x25 local-window prefix
static constexpr int NRND = SSAM - NLOC;   // 399 random samples
static constexpr int ROWS_PER_BLOCK = 16;  // gather kernel

__device__ __forceinline__ uint16_t f2h(float f) {
    union { _Float16 h; uint16_t u; } c;
    c.h = (_Float16)f;
    return c.u;
}

template<int CTRL>
__device__ __forceinline__ float dpp_add(float x) {
    int y = __builtin_amdgcn_mov_dpp(__float_as_int(x), CTRL, 0xF, 0xF, true);
    return x + __int_as_float(y);
}

__device__ __forceinline__ float dot2(h2 a, h2 b, float c) {
    return __builtin_amdgcn_fdot2(a, b, c, false);   // v_dot2_f32_f16
}

// ---------------------------------------------------------------------------
// Kernel 1: layout prep. key/query [B][C][N] f32 -> [B*N][32] f16 rows (64B);
// query pre-scaled by C^-0.5. Emits seg8; zeroes segbit (2 words/thread).
// ---------------------------------------------------------------------------
__global__ __launch_bounds__(256)
void prep_kernel(const float* __restrict__ key_f,
                 const float* __restrict__ query_f,
                 const int* __restrict__ seg32,
                 uint8_t* __restrict__ key16,
                 uint8_t* __restrict__ q16,
                 uint8_t* __restrict__ seg8,
                 uint32_t* __restrict__ segbit,
                 int N, int rows, float scale)
{
    int gI = blockIdx.x * 256 + threadIdx.x;
    if (gI >= rows) return;
    segbit[2 * gI]     = 0;
    segbit[2 * gI + 1] = 0;
    seg8[gI] = (uint8_t)seg32[gI];

    int b = gI / N, n = gI - b * N;
    const size_t cb = (size_t)b * CDIM;

    uint32_t kp[16], qp[16];
#pragma unroll
    for (int c = 0; c < CDIM; c += 2) {
        float k0 = key_f[(cb + c) * N + n];
        float k1 = key_f[(cb + c + 1) * N + n];
        float q0 = query_f[(cb + c) * N + n] * scale;
        float q1 = query_f[(cb + c + 1) * N + n] * scale;
        kp[c >> 1] = (uint32_t)f2h(k0) | ((uint32_t)f2h(k1) << 16);
        qp[c >> 1] = (uint32_t)f2h(q0) | ((uint32_t)f2h(q1) << 16);
    }
    uint4* ko = (uint4*)(key16 + ((size_t)gI << 6));
    uint4* qo = (uint4*)(q16 + ((size_t)gI << 6));
#pragma unroll
    for (int j = 0; j < 4; ++j) {
        ko[j] = make_uint4(kp[4*j], kp[4*j+1], kp[4*j+2], kp[4*j+3]);
        qo[j] = make_uint4(qp[4*j], qp[4*j+1], qp[4*j+2], qp[4*j+3]);
    }
}

// ---------------------------------------------------------------------------
// Kernel 1b: segment bitmap. segbit[b][v][512]: bit n set iff seg[b][n]==v.
// ---------------------------------------------------------------------------
__global__ __launch_bounds__(256)
void segbit_build(const int* __restrict__ seg32,
                  uint32_t* __restrict__ segbit,
                  int N, int rows)
{
    int g = blockIdx.x * 256 + threadIdx.x;
    if (g >= rows) return;
    int b = g / N, n = g - b * N;
    int v = seg32[g] & 63;
    atomicOr(&segbit[(((size_t)(b * 64 + v)) << 9) + (n >> 5)], 1u << (n & 31));
}

// ---------------------------------------------------------------------------
// Kernel A: dense local logits for s < 625 (full 25x25 local window prefix).
// One block per 8x8 query tile; clamped 32x32 key window staged strip-by-
// strip (8 rows = 20KB); 64x256x32 GEMM per strip via 2x
// v_mfma_f32_16x16x16_f16; results in wave-private f16 LDS (32KB; logits
// |<~8| so f16 round ~0.004 << threshold). Total LDS ~54KB -> 2 blocks/CU
// (R12's f32 res forced 1/CU = its 60us cost). Selection writes logits and
// accumulates (Z,T,SL) per row.
// ---------------------------------------------------------------------------
__global__ __launch_bounds__(256)
void dense_local(const uint8_t* __restrict__ key16,
                 const uint8_t* __restrict__ q16,
                 const uint8_t* __restrict__ seg8,
                 float* __restrict__ out,
                 float* __restrict__ zA,
                 float* __restrict__ tA,
                 float* __restrict__ slA)
{
    const int tid  = threadIdx.x;
    const int bid  = blockIdx.x;
    const int b    = bid >> 8;             // 256 tiles per image
    const int t8   = bid & 255;
    const int y0   = (t8 >> 4) << 3;
    const int x0   = (t8 & 15) << 3;
    const int lane = tid & 63;
    const int w    = tid >> 6;

    __shared__ __align__(16) uint8_t  kslot[256 * 80];    // 20KB strip keys
    __shared__ __align__(16) _Float16 res[4][16][256];    // 32KB wave-private
    __shared__ uint8_t wseg[1024];                        // window seg
    __shared__ float   rowacc[4][16][3];                  // Z,T,SL per query

    const uint8_t* kb = key16 + ((size_t)b << 20);
    const uint8_t* sb = seg8 + ((size_t)b << 14);
    const int yo = y0 - 12, xo = x0 - 12;                 // unclamped origin

    // stage window seg (clamped)
    for (int s = tid; s < 1024; s += 256) {
        int i = s >> 5, j = s & 31;
        int yy = min(max(yo + i, 0), 127);
        int xx = min(max(xo + j, 0), 127);
        wseg[s] = sb[(yy << 7) + xx];
    }
    if (tid < 192) ((float*)rowacc)[tid] = 0.f;

    // A fragments, once: wave w owns queries 16w..16w+15
    const int qsel = (w << 4) + (lane & 15);
    const int qyA  = qsel >> 3, qxA = qsel & 7;
    const size_t qrow = ((size_t)b << 14) + ((size_t)(y0 + qyA) << 7) + (x0 + qxA);
    const int koff = (lane >> 4) << 3;                    // 8*(lane/16) bytes
    const h4 a0 = *(const h4*)(q16 + (qrow << 6) + koff);
    const h4 a1 = *(const h4*)(q16 + (qrow << 6) + 32 + koff);

    __syncthreads();    // wseg + rowacc visible

    for (int t = 0; t < 4; ++t) {
        // stage strip keys
        for (int s = tid; s < 1024; s += 256) {
            int slot = s >> 2, q = s & 3;
            int i = (t << 3) + (slot >> 5), j = slot & 31;
            int yy = min(max(yo + i, 0), 127);
            int xx = min(max(xo + j, 0), 127);
            *(uint4*)(kslot + slot * 80 + (q << 4)) =
                *(const uint4*)(kb + ((((size_t)(yy << 7)) + xx) << 6) + (q << 4));
        }
        __syncthreads();

        // GEMM: 16 N-tiles of 16 window slots each
#pragma unroll 4
        for (int n = 0; n < 16; ++n) {
            const uint8_t* kr = kslot + ((n << 4) + (lane & 15)) * 80;
            h4 b0 = *(const h4*)(kr + koff);
            h4 b1 = *(const h4*)(kr + 32 + koff);
            f4 acc = {0.f, 0.f, 0.f, 0.f};
            acc = __builtin_amdgcn_mfma_f32_16x16x16f16(a0, b0, acc, 0, 0, 0);
            acc = __builtin_amdgcn_mfma_f32_16x16x16f16(a1, b1, acc, 0, 0, 0);
#pragma unroll
            for (int r = 0; r < 4; ++r)
                res[w][((lane >> 4) << 2) + r][(n << 4) + (lane & 15)] =
                    (_Float16)acc[r];
        }

        // selection: wave's 16 rows, contiguous s-span for this strip
        for (int m = 0; m < 16; ++m) {
            const int q  = (w << 4) + m;
            const int qy = q >> 3, qx = q & 7;
            const int row = (b << 14) + ((y0 + qy) << 7) + (x0 + qx);
            const int segr = (int)wseg[((qy + 12) << 5) + qx + 12];
            int sLo = ((t << 3) - qy) * 25; if (sLo < 0) sLo = 0;
            int sHi = ((t << 3) - qy + 8) * 25; if (sHi > NLOC) sHi = NLOC;
            float z = 0.f, tc = 0.f, sl = 0.f;
            for (int s = sLo + lane; s < sHi; s += 64) {
                int d25 = (s * 5243) >> 17;          // s/25 (exact here)
                int r25 = s - d25 * 25;              // s%25
                int i  = qy + d25;                   // window row
                int wc = qx + r25;                   // window col
                float v = (float)res[w][m][((i - (t << 3)) << 5) + wc];
                out[((size_t)row << 10) + s] = v;    // coalesced 64-lane run
                z += __expf(v);
                if ((int)wseg[(i << 5) + wc] == segr) { tc += 1.f; sl += v; }
            }
#pragma unroll
            for (int off = 32; off >= 1; off >>= 1) {
                z  += __shfl_xor(z,  off, 64);
                tc += __shfl_xor(tc, off, 64);
                sl += __shfl_xor(sl, off, 64);
            }
            if (lane == 0) {
                rowacc[w][m][0] += z;
                rowacc[w][m][1] += tc;
                rowacc[w][m][2] += sl;
            }
        }
        __syncthreads();    // all waves done before next strip restages kslot
    }

    if (tid < 64) {
        int q = tid, qy = q >> 3, qx = q & 7;
        int row = (b << 14) + ((y0 + qy) << 7) + (x0 + qx);
        zA[row]  = rowacc[q >> 4][q & 15][0];
        tA[row]  = rowacc[q >> 4][q & 15][1];
        slA[row] = rowacc[q >> 4][q & 15][2];
    }
}

// ---------------------------------------------------------------------------
// Kernel B: gathered logits for s in [625,1024) — 399 random samples.
// R9 skeleton: 16-row persistent blocks, one barrier/row, segbit targets,
// closed-form KL merged with kernel A's partials. 7 gather iters x 64 groups
// (last iter: only gidx<15 active). Lines/row = 399 (vs 512 in R12).
// ---------------------------------------------------------------------------
__global__ __launch_bounds__(256)
void affinity_rand(const int* __restrict__ inds,
                   const uint8_t* __restrict__ key16,
                   const uint8_t* __restrict__ q16,
                   const int* __restrict__ seg32,
                   const uint32_t* __restrict__ segbit,
                   const float* __restrict__ zA,
                   const float* __restrict__ tA,
                   const float* __restrict__ slA,
                   float* __restrict__ out,
                   float* __restrict__ ws_kl)
{
    const int tid  = threadIdx.x;
    const int row0 = blockIdx.x * ROWS_PER_BLOCK;
    const int b    = row0 >> 14;
    const int lane = tid & 63;
    const int w    = tid >> 6;
    const int g    = lane >> 2;
    const int sub  = lane & 3;
    const int gidx = (w << 4) + g;         // block-wide group 0..63

    __shared__ __align__(16) int      idx_lds[2][448];   // 399 used
    __shared__ __align__(16) uint32_t bm_lds[2][512];
    __shared__ float red[2][3][4];
    __shared__ float zp[ROWS_PER_BLOCK], tp[ROWS_PER_BLOCK], sp[ROWS_PER_BLOCK];

    const uint32_t* sbase_bm = segbit + ((size_t)(b * 64) << 9);

    // prologue: dense partials + row0 state
    if (tid < ROWS_PER_BLOCK)           zp[tid] = zA[row0 + tid];
    else if (tid < 2*ROWS_PER_BLOCK)    tp[tid - ROWS_PER_BLOCK] = tA[row0 + tid - ROWS_PER_BLOCK];
    else if (tid < 3*ROWS_PER_BLOCK)    sp[tid - 2*ROWS_PER_BLOCK] = slA[row0 + tid - 2*ROWS_PER_BLOCK];

    {
        const int* ib = inds + ((size_t)row0 << 10) + NLOC;
        idx_lds[0][tid] = ib[tid];
        if (tid < NRND - 256) idx_lds[0][256 + tid] = ib[256 + tid];
    }
    int scur = seg32[row0];
    ((uint2*)bm_lds[0])[tid] =
        ((const uint2*)(sbase_bm + ((size_t)(scur & 63) << 9)))[tid];
    uint4 qcur = *(const uint4*)(q16 + ((size_t)row0 << 6) + (sub << 4));
    __syncthreads();

    const uint8_t* kb = key16 + ((size_t)b << 20);
    const uint32_t subs = (uint32_t)(sub << 4);
    const bool act6 = (384 + gidx) < NRND;              // gidx < 15

    for (int r = 0; r < ROWS_PER_BLOCK; ++r) {
        const int row = row0 + r;
        const int p   = r & 1;
        const int* cur = idx_lds[p];
        const bool hasNext = (r + 1 < ROWS_PER_BLOCK);

        h2 qh0, qh1, qh2, qh3;
        {
            union { uint4 u; h2 h[4]; } qc; qc.u = qcur;
            qh0 = qc.h[0]; qh1 = qc.h[1]; qh2 = qc.h[2]; qh3 = qc.h[3];
        }
        const int seg_n = scur;

        // ---- phase 1: indices; phase 2: gathers (7 deep, tail masked) ----
        int idxs[7];
#pragma unroll
        for (int i = 0; i < 7; ++i)
            idxs[i] = cur[(i << 6) + gidx];

        uint4 kd[7];
#pragma unroll
        for (int i = 0; i < 6; ++i)
            kd[i] = *(const uint4*)(kb + (((uint32_t)idxs[i] << 6) | subs));
        kd[6] = make_uint4(0, 0, 0, 0);
        if (act6)
            kd[6] = *(const uint4*)(kb + (((uint32_t)idxs[6] << 6) | subs));

        // ---- latency cover: next-row prefetch + bitmap target flags ----
        int pre0 = 0, pre1 = 0; uint4 qnext; uint2 pre_bm; int snext;
        if (hasNext) {
            const int* ib = inds + ((size_t)(row + 1) << 10) + NLOC;
            pre0 = ib[tid];
            if (tid < NRND - 256) pre1 = ib[256 + tid];
            qnext  = *(const uint4*)(q16 + ((size_t)(row + 1) << 6) + (sub << 4));
            snext  = seg32[row + 1];
            pre_bm = ((const uint2*)(sbase_bm + ((size_t)(snext & 63) << 9)))[tid];
        }
        // ownership: lane owns pos0 = sub*64+gidx (always <399) and
        // pos1 = (sub+4)*64+gidx (exists iff sub<3; active iff pos1<399)
        const bool owned1 = (sub < 2) || (sub == 2 && act6);
        int tfm = 0;
        {
            int idx0 = cur[(sub << 6) + gidx];
            if ((bm_lds[p][idx0 >> 5] >> (idx0 & 31)) & 1u) tfm |= 1;
            if (sub < 3) {
                int idx1 = cur[((sub + 4) << 6) + gidx];
                if (owned1 && ((bm_lds[p][idx1 >> 5] >> (idx1 & 31)) & 1u))
                    tfm |= 2;
            }
        }

        // ---- phase 3: dots + quad reduce + owner capture + stores ----
        const size_t obase = ((size_t)row << 10) + NLOC;
        float lg0 = 0.f, lg1 = 0.f;
#pragma unroll
        for (int it = 0; it < 7; ++it) {
            union { uint4 u; h2 h[4]; } kc; kc.u = kd[it];
            float acc = dot2(kc.h[0], qh0, 0.f);
            acc = dot2(kc.h[1], qh1, acc);
            acc = dot2(kc.h[2], qh2, acc);
            acc = dot2(kc.h[3], qh3, acc);
            acc = dpp_add<0xB1>(acc);
            acc = dpp_add<0x4E>(acc);
            if (sub == (it & 3)) {
                if (it < 4) lg0 = acc;
                else        lg1 = acc;
                if (it < 6 || act6)
                    out[obase + (it << 6) + gidx] = acc;
            }
        }

        float z  = __expf(lg0) + (owned1 ? __expf(lg1) : 0.f);
        float tc = (float)__popc((unsigned)tfm);
        float sl = ((tfm & 1) ? lg0 : 0.f) + ((tfm & 2) ? lg1 : 0.f);
#pragma unroll
        for (int off = 32; off >= 1; off >>= 1) {
            z  += __shfl_xor(z,  off, 64);
            tc += __shfl_xor(tc, off, 64);
            sl += __shfl_xor(sl, off, 64);
        }
        if (lane == 0) {
            red[p][0][w] = z;
            red[p][1][w] = tc;
            red[p][2][w] = sl;
        }

        // ---- commit prefetch into the other parity slots ----
        if (hasNext) {
            idx_lds[p ^ 1][tid] = pre0;
            if (tid < NRND - 256) idx_lds[p ^ 1][256 + tid] = pre1;
            ((uint2*)bm_lds[p ^ 1])[tid] = pre_bm;
            qcur = qnext;
            scur = snext;
        }
        __syncthreads();                   // the one barrier per row

        if (tid == 0) {
            if (seg_n != 0) {
                const float Z  = zp[r] + (red[p][0][0] + red[p][0][1]) + (red[p][0][2] + red[p][0][3]);
                const float T  = tp[r] + (red[p][1][0] + red[p][1][1]) + (red[p][1][2] + red[p][1][3]);
                const float SL = sp[r] + (red[p][2][0] + red[p][2][1]) + (red[p][2][2] + red[p][2][3]);
                // closed-form KL; T >= 1 (center sample matches itself)
                ws_kl[row] = -__logf(T) - SL / T + __logf(Z);
            } else {
                ws_kl[row] = 0.f;
            }
        }
    }
}

// ---------------------------------------------------------------------------
// Fallback (generic shapes / tiny ws): per-thread gather from native layout.
// ---------------------------------------------------------------------------
__global__ __launch_bounds__(256)
void affinity_fallback(const float* __restrict__ key_f,
                       const float* __restrict__ query_f,
                       const int*   __restrict__ seg32,
                       const int*   __restrict__ inds,
                       float* __restrict__ out,
                       float* __restrict__ ws_kl,
                       int N, int S, float scale)
{
    const int bid = blockIdx.x;
    const int tid = threadIdx.x;
    const int b   = bid / N;

    __shared__ float q_lds[CDIM];
    __shared__ float redA[4], redB[4], redC[4];

    if (tid < CDIM) {
        int n = bid - b * N;
        q_lds[tid] = query_f[((size_t)(b * CDIM + tid)) * N + n];
    }
    const int seg_n = seg32[bid];
    __syncthreads();

    float q[CDIM];
#pragma unroll
    for (int c = 0; c < CDIM; ++c) q[c] = q_lds[c];

    const size_t rowbase = (size_t)bid * S;
    const int4 iv = ((const int4*)(inds + rowbase))[tid];
    const int idxv[4] = {iv.x, iv.y, iv.z, iv.w};

    float lg[4];
    int   tf[4];
#pragma unroll
    for (int k = 0; k < 4; ++k) {
        int idx = idxv[k];
        tf[k] = (seg32[b * N + idx] == seg_n) ? 1 : 0;
        float acc = 0.f;
#pragma unroll
        for (int c = 0; c < CDIM; ++c)
            acc = fmaf(key_f[((size_t)(b * CDIM + c)) * N + idx], q[c], acc);
        lg[k] = acc * scale;
    }
    ((float4*)(out + rowbase))[tid] = make_float4(lg[0], lg[1], lg[2], lg[3]);

    const int lane = tid & 63, wv = tid >> 6;
    float m = fmaxf(fmaxf(lg[0], lg[1]), fmaxf(lg[2], lg[3]));
#pragma unroll
    for (int off = 32; off >= 1; off >>= 1)
        m = fmaxf(m, __shfl_xor(m, off, 64));
    if (lane == 0) redA[wv] = m;
    __syncthreads();
    m = fmaxf(fmaxf(redA[0], redA[1]), fmaxf(redA[2], redA[3]));

    float e[4], z = 0.f, tcnt = 0.f;
#pragma unroll
    for (int k = 0; k < 4; ++k) {
        e[k] = expf(lg[k] - m);
        z += e[k];
        tcnt += (float)tf[k];
    }
#pragma unroll
    for (int off = 32; off >= 1; off >>= 1) {
        z    += __shfl_xor(z, off, 64);
        tcnt += __shfl_xor(tcnt, off, 64);
    }
    if (lane == 0) { redB[wv] = z; redC[wv] = tcnt; }
    __syncthreads();
    const float Z = redB[0] + redB[1] + redB[2] + redB[3];
    const float T = redC[0] + redC[1] + redC[2] + redC[3];

    float kl = 0.f;
    if (seg_n != 0) {
        const float invZ = 1.f / (Z + 1e-9f);
        const float invT = 1.f / (T + 1e-9f);
        const float nlT  = -logf(T + 1e-9f);
#pragma unroll
        for (int k = 0; k < 4; ++k) {
            if (tf[k]) {
                float p = e[k] * invZ;
                float yp = logf(fmaxf(p, 1e-8f));
                kl += invT * (nlT - yp);
            }
        }
    }
#pragma unroll
    for (int off = 32; off >= 1; off >>= 1)
        kl += __shfl_xor(kl, off, 64);
    if (lane == 0) redA[wv] = kl;
    __syncthreads();
    if (tid == 0)
        ws_kl[bid] = redA[0] + redA[1] + redA[2] + redA[3];
}

// ---------------------------------------------------------------------------
// Kernel 3: deterministic single-block loss reduction (1024 threads).
// ---------------------------------------------------------------------------
__global__ __launch_bounds__(1024)
void loss_reduce(const float* __restrict__ ws_kl,
                 const int* __restrict__ seg32,
                 float* __restrict__ out_loss, int rows)
{
    const int tid = threadIdx.x;
    float s = 0.f, c = 0.f;
    for (int i = tid; i < rows; i += 1024) {
        s += ws_kl[i];
        c += (seg32[i] != 0) ? 1.f : 0.f;
    }
#pragma unroll
    for (int off = 32; off >= 1; off >>= 1) {
        s += __shfl_xor(s, off, 64);
        c += __shfl_xor(c, off, 64);
    }
    __shared__ float sA[16], sB[16];
    const int lane = tid & 63, wv = tid >> 6;
    if (lane == 0) { sA[wv] = s; sB[wv] = c; }
    __syncthreads();
    if (tid == 0) {
        float ts = 0.f, tc = 0.f;
#pragma unroll
        for (int k = 0; k < 16; ++k) { ts += sA[k]; tc += sB[k]; }
        out_loss[0] = ts / (tc + 1e-9f);
    }
}

// ---------------------------------------------------------------------------
extern "C" void kernel_launch(void* const* d_in, const int* in_sizes, int n_in,
                              void* d_out, int out_size, void* d_ws, size_t ws_size,
                              hipStream_t stream)
{
    const float* key_f   = (const float*)d_in[0];
    const float* query_f = (const float*)d_in[1];
    const int*   seg32   = (const int*)d_in[2];
    const int*   inds    = (const int*)d_in[3];
    float* out = (float*)d_out;

    const int N    = NPIX;
    const int rows = in_sizes[2];            // B*N
    const int S    = in_sizes[3] / rows;     // 1024
    const float scale = (float)(1.0 / sqrt((double)CDIM));
    const int B    = rows / N;

    // ws: key16 | q16 | seg8 | segbit | zA | tA | slA | kl
    const size_t off_q16 = (size_t)rows * 64;
    const size_t off_s8  = off_q16 + (size_t)rows * 64;
    const size_t off_sb  = (off_s8 + (size_t)rows + 255) & ~(size_t)255;
    const size_t sb_words = (size_t)B * 64 * 512;     // == 2*rows
    const size_t off_zA  = (off_sb + sb_words * 4 + 255) & ~(size_t)255;
    const size_t off_tA  = off_zA + (size_t)rows * 4;
    const size_t off_slA = off_tA + (size_t)rows * 4;
    const size_t off_kl  = off_slA + (size_t)rows * 4;
    const size_t need    = off_kl + (size_t)rows * 4;

    uint8_t* wsb = (uint8_t*)d_ws;
    const bool geom_ok = (S == SSAM) && (rows % N == 0) &&
                         (rows % ROWS_PER_BLOCK == 0);

    if (ws_size >= need && geom_ok) {
        uint8_t*  key16  = wsb;
        uint8_t*  q16    = wsb + off_q16;
        uint8_t*  seg8   = wsb + off_s8;
        uint32_t* segbit = (uint32_t*)(wsb + off_sb);
        float*    zA     = (float*)(wsb + off_zA);
        float*    tA     = (float*)(wsb + off_tA);
        float*    slA    = (float*)(wsb + off_slA);
        float*    wskl   = (float*)(wsb + off_kl);

        prep_kernel<<<(rows + 255) / 256, 256, 0, stream>>>(
            key_f, query_f, seg32, key16, q16, seg8, segbit, N, rows, scale);
        segbit_build<<<(rows + 255) / 256, 256, 0, stream>>>(
            seg32, segbit, N, rows);
        dense_local<<<B * 256, 256, 0, stream>>>(
            key16, q16, seg8, out, zA, tA, slA);
        affinity_rand<<<rows / ROWS_PER_BLOCK, 256, 0, stream>>>(
            inds, key16, q16, seg32, segbit, zA, tA, slA, out, wskl);
        loss_reduce<<<1, 1024, 0, stream>>>(wskl, seg32, out + (size_t)rows * S, rows);
    } else {
        float* wskl = (float*)d_ws;
        affinity_fallback<<<rows, 256, 0, stream>>>(
            key_f, query_f, seg32, inds, out, wskl, N, S, scale);
        loss_reduce<<<1, 1024, 0, stream>>>(wskl, seg32, out + (size_t)rows * S, rows);
    }
}

// Round 16
// 165.461 us; speedup vs baseline: 1.2273x; 1.0011x over previous
//
#include <hip/hip_runtime.h>
#include <stdint.h>

typedef _Float16 h2 __attribute__((ext_vector_type(2)));
typedef _Float16 h4 __attribute__((ext_vector_type(4)));
typedef float    f4 __attribute__((ext_vector_type(4)));

static constexpr int CDIM = 32;     // channels
static constexpr int NPIX = 16384;  // H*W = 128*128
static constexpr int SSAM = 1024;   // samples per row
static constexpr int NLOC = 625;    // 25x25 local-window prefix
static constexpr int NRND = SSAM - NLOC;   // 399 random samples
static constexpr int ROWS_PER_BLOCK = 16;  // gather kernel (8 pairs)

__device__ __forceinline__ uint16_t f2h(float f) {
    union { _Float16 h; uint16_t u; } c;
    c.h = (_Float16)f;
    return c.u;
}

template<int CTRL>
__device__ __forceinline__ float dpp_add(float x) {
    int y = __builtin_amdgcn_mov_dpp(__float_as_int(x), CTRL, 0xF, 0xF, true);
    return x + __int_as_float(y);
}

__device__ __forceinline__ float dot2(h2 a, h2 b, float c) {
    return __builtin_amdgcn_fdot2(a, b, c, false);   // v_dot2_f32_f16
}

// ---------------------------------------------------------------------------
// Kernel 1: layout prep. key/query [B][C][N] f32 -> [B*N][32] f16 rows (64B);
// query pre-scaled by C^-0.5. Emits seg8; zeroes segbit (2 words/thread).
// ---------------------------------------------------------------------------
__global__ __launch_bounds__(256)
void prep_kernel(const float* __restrict__ key_f,
                 const float* __restrict__ query_f,
                 const int* __restrict__ seg32,
                 uint8_t* __restrict__ key16,
                 uint8_t* __restrict__ q16,
                 uint8_t* __restrict__ seg8,
                 uint32_t* __restrict__ segbit,
                 int N, int rows, float scale)
{
    int gI = blockIdx.x * 256 + threadIdx.x;
    if (gI >= rows) return;
    segbit[2 * gI]     = 0;
    segbit[2 * gI + 1] = 0;
    seg8[gI] = (uint8_t)seg32[gI];

    int b = gI / N, n = gI - b * N;
    const size_t cb = (size_t)b * CDIM;

    uint32_t kp[16], qp[16];
#pragma unroll
    for (int c = 0; c < CDIM; c += 2) {
        float k0 = key_f[(cb + c) * N + n];
        float k1 = key_f[(cb + c + 1) * N + n];
        float q0 = query_f[(cb + c) * N + n] * scale;
        float q1 = query_f[(cb + c + 1) * N + n] * scale;
        kp[c >> 1] = (uint32_t)f2h(k0) | ((uint32_t)f2h(k1) << 16);
        qp[c >> 1] = (uint32_t)f2h(q0) | ((uint32_t)f2h(q1) << 16);
    }
    uint4* ko = (uint4*)(key16 + ((size_t)gI << 6));
    uint4* qo = (uint4*)(q16 + ((size_t)gI << 6));
#pragma unroll
    for (int j = 0; j < 4; ++j) {
        ko[j] = make_uint4(kp[4*j], kp[4*j+1], kp[4*j+2], kp[4*j+3]);
        qo[j] = make_uint4(qp[4*j], qp[4*j+1], qp[4*j+2], qp[4*j+3]);
    }
}

// ---------------------------------------------------------------------------
// Kernel 1b: segment bitmap. segbit[b][v][512]: bit n set iff seg[b][n]==v.
// ---------------------------------------------------------------------------
__global__ __launch_bounds__(256)
void segbit_build(const int* __restrict__ seg32,
                  uint32_t* __restrict__ segbit,
                  int N, int rows)
{
    int g = blockIdx.x * 256 + threadIdx.x;
    if (g >= rows) return;
    int b = g / N, n = g - b * N;
    int v = seg32[g] & 63;
    atomicOr(&segbit[(((size_t)(b * 64 + v)) << 9) + (n >> 5)], 1u << (n & 31));
}

// ---------------------------------------------------------------------------
// Kernel A: dense local logits for s < 625 (full 25x25 local window prefix).
// Unchanged from R13 (passed, ~30-35us).
// ---------------------------------------------------------------------------
__global__ __launch_bounds__(256)
void dense_local(const uint8_t* __restrict__ key16,
                 const uint8_t* __restrict__ q16,
                 const uint8_t* __restrict__ seg8,
                 float* __restrict__ out,
                 float* __restrict__ zA,
                 float* __restrict__ tA,
                 float* __restrict__ slA)
{
    const int tid  = threadIdx.x;
    const int bid  = blockIdx.x;
    const int b    = bid >> 8;             // 256 tiles per image
    const int t8   = bid & 255;
    const int y0   = (t8 >> 4) << 3;
    const int x0   = (t8 & 15) << 3;
    const int lane = tid & 63;
    const int w    = tid >> 6;

    __shared__ __align__(16) uint8_t  kslot[256 * 80];    // 20KB strip keys
    __shared__ __align__(16) _Float16 res[4][16][256];    // 32KB wave-private
    __shared__ uint8_t wseg[1024];                        // window seg
    __shared__ float   rowacc[4][16][3];                  // Z,T,SL per query

    const uint8_t* kb = key16 + ((size_t)b << 20);
    const uint8_t* sb = seg8 + ((size_t)b << 14);
    const int yo = y0 - 12, xo = x0 - 12;                 // unclamped origin

    for (int s = tid; s < 1024; s += 256) {
        int i = s >> 5, j = s & 31;
        int yy = min(max(yo + i, 0), 127);
        int xx = min(max(xo + j, 0), 127);
        wseg[s] = sb[(yy << 7) + xx];
    }
    if (tid < 192) ((float*)rowacc)[tid] = 0.f;

    const int qsel = (w << 4) + (lane & 15);
    const int qyA  = qsel >> 3, qxA = qsel & 7;
    const size_t qrow = ((size_t)b << 14) + ((size_t)(y0 + qyA) << 7) + (x0 + qxA);
    const int koff = (lane >> 4) << 3;                    // 8*(lane/16) bytes
    const h4 a0 = *(const h4*)(q16 + (qrow << 6) + koff);
    const h4 a1 = *(const h4*)(q16 + (qrow << 6) + 32 + koff);

    __syncthreads();

    for (int t = 0; t < 4; ++t) {
        for (int s = tid; s < 1024; s += 256) {
            int slot = s >> 2, q = s & 3;
            int i = (t << 3) + (slot >> 5), j = slot & 31;
            int yy = min(max(yo + i, 0), 127);
            int xx = min(max(xo + j, 0), 127);
            *(uint4*)(kslot + slot * 80 + (q << 4)) =
                *(const uint4*)(kb + ((((size_t)(yy << 7)) + xx) << 6) + (q << 4));
        }
        __syncthreads();

#pragma unroll 4
        for (int n = 0; n < 16; ++n) {
            const uint8_t* kr = kslot + ((n << 4) + (lane & 15)) * 80;
            h4 b0 = *(const h4*)(kr + koff);
            h4 b1 = *(const h4*)(kr + 32 + koff);
            f4 acc = {0.f, 0.f, 0.f, 0.f};
            acc = __builtin_amdgcn_mfma_f32_16x16x16f16(a0, b0, acc, 0, 0, 0);
            acc = __builtin_amdgcn_mfma_f32_16x16x16f16(a1, b1, acc, 0, 0, 0);
#pragma unroll
            for (int r = 0; r < 4; ++r)
                res[w][((lane >> 4) << 2) + r][(n << 4) + (lane & 15)] =
                    (_Float16)acc[r];
        }

        for (int m = 0; m < 16; ++m) {
            const int q  = (w << 4) + m;
            const int qy = q >> 3, qx = q & 7;
            const int row = (b << 14) + ((y0 + qy) << 7) + (x0 + qx);
            const int segr = (int)wseg[((qy + 12) << 5) + qx + 12];
            int sLo = ((t << 3) - qy) * 25; if (sLo < 0) sLo = 0;
            int sHi = ((t << 3) - qy + 8) * 25; if (sHi > NLOC) sHi = NLOC;
            float z = 0.f, tc = 0.f, sl = 0.f;
            for (int s = sLo + lane; s < sHi; s += 64) {
                int d25 = (s * 5243) >> 17;          // s/25 (exact here)
                int r25 = s - d25 * 25;              // s%25
                int i  = qy + d25;
                int wc = qx + r25;
                float v = (float)res[w][m][((i - (t << 3)) << 5) + wc];
                out[((size_t)row << 10) + s] = v;
                z += __expf(v);
                if ((int)wseg[(i << 5) + wc] == segr) { tc += 1.f; sl += v; }
            }
#pragma unroll
            for (int off = 32; off >= 1; off >>= 1) {
                z  += __shfl_xor(z,  off, 64);
                tc += __shfl_xor(tc, off, 64);
                sl += __shfl_xor(sl, off, 64);
            }
            if (lane == 0) {
                rowacc[w][m][0] += z;
                rowacc[w][m][1] += tc;
                rowacc[w][m][2] += sl;
            }
        }
        __syncthreads();
    }

    if (tid < 64) {
        int q = tid, qy = q >> 3, qx = q & 7;
        int row = (b << 14) + ((y0 + qy) << 7) + (x0 + qx);
        zA[row]  = rowacc[q >> 4][q & 15][0];
        tA[row]  = rowacc[q >> 4][q & 15][1];
        slA[row] = rowacc[q >> 4][q & 15][2];
    }
}

// ---------------------------------------------------------------------------
// Kernel B: gathered logits for s in [625,1024), PAIRED ROWS.
// R14 structure with the staging bug FIXED: each 128-thread half must cover
// all 399 indices -> 4 chunks (ht, +128, +256, +384 if ht<15). R14 covered
// only 0..383, leaving 384..398 garbage -> wild gather -> memory fault.
// 2 rows/iter: half-block staging, 14 shared-window gathers, 6 parallel
// butterfly chains, ONE barrier per pair, tid 0/1 finalize both KLs.
// ---------------------------------------------------------------------------
__global__ __launch_bounds__(256)
void affinity_rand(const int* __restrict__ inds,
                   const uint8_t* __restrict__ key16,
                   const uint8_t* __restrict__ q16,
                   const int* __restrict__ seg32,
                   const uint32_t* __restrict__ segbit,
                   const float* __restrict__ zA,
                   const float* __restrict__ tA,
                   const float* __restrict__ slA,
                   float* __restrict__ out,
                   float* __restrict__ ws_kl)
{
    const int tid  = threadIdx.x;
    const int row0 = blockIdx.x * ROWS_PER_BLOCK;
    const int b    = row0 >> 14;
    const int lane = tid & 63;
    const int w    = tid >> 6;
    const int g    = lane >> 2;
    const int sub  = lane & 3;
    const int gidx = (w << 4) + g;         // block-wide group 0..63
    const int half = tid >> 7;             // row within pair this thread stages
    const int ht   = tid & 127;

    __shared__ __align__(16) int      idx_lds[2][2][448];  // [pairpar][row][s]
    __shared__ __align__(16) uint32_t bm_lds[2][2][512];
    __shared__ float red[2][6][4];         // [pairpar][ZTS x 2 rows][wave]
    __shared__ float zp[ROWS_PER_BLOCK], tp[ROWS_PER_BLOCK], sp[ROWS_PER_BLOCK];

    const uint32_t* sbm = segbit + ((size_t)(b * 64) << 9);

    // prologue: dense partials + pair-0 state
    if (tid < ROWS_PER_BLOCK)             zp[tid] = zA[row0 + tid];
    else if (tid < 2*ROWS_PER_BLOCK)      tp[tid - ROWS_PER_BLOCK] = tA[row0 + tid - ROWS_PER_BLOCK];
    else if (tid < 3*ROWS_PER_BLOCK)      sp[tid - 2*ROWS_PER_BLOCK] = slA[row0 + tid - 2*ROWS_PER_BLOCK];

    {
        const int* ib = inds + ((size_t)(row0 + half) << 10) + NLOC;
        idx_lds[0][half][ht]       = ib[ht];
        idx_lds[0][half][ht + 128] = ib[ht + 128];
        idx_lds[0][half][ht + 256] = ib[ht + 256];          // 256..383 (<399)
        if (ht < NRND - 384)                                 // 384..398
            idx_lds[0][half][ht + 384] = ib[ht + 384];
        int sh = seg32[row0 + half];
        ((uint4*)bm_lds[0][half])[ht] =
            ((const uint4*)(sbm + ((size_t)(sh & 63) << 9)))[ht];
    }
    int scurA = seg32[row0];
    int scurB = seg32[row0 + 1];
    uint4 qcurA = *(const uint4*)(q16 + ((size_t)row0 << 6) + (sub << 4));
    uint4 qcurB = *(const uint4*)(q16 + ((size_t)(row0 + 1) << 6) + (sub << 4));
    __syncthreads();

    const uint8_t* kp = key16 + ((size_t)b << 20);
    const uint32_t subs = (uint32_t)(sub << 4);
    const bool act6 = (384 + gidx) < NRND;              // gidx < 15
    const bool owned1 = (sub < 2) || (sub == 2 && act6);

    for (int t = 0; t < ROWS_PER_BLOCK / 2; ++t) {
        const int rowA = row0 + 2 * t;
        const int rowB = rowA + 1;
        const int pp   = t & 1;
        const int* curA = idx_lds[pp][0];
        const int* curB = idx_lds[pp][1];
        const bool hasNext = (t + 1 < ROWS_PER_BLOCK / 2);

        h2 qa0, qa1, qa2, qa3, qb0, qb1, qb2, qb3;
        {
            union { uint4 u; h2 h[4]; } qc;
            qc.u = qcurA; qa0 = qc.h[0]; qa1 = qc.h[1]; qa2 = qc.h[2]; qa3 = qc.h[3];
            qc.u = qcurB; qb0 = qc.h[0]; qb1 = qc.h[1]; qb2 = qc.h[2]; qb3 = qc.h[3];
        }
        const int segA = scurA, segB = scurB;

        // ---- indices for both rows ----
        int ixA[7], ixB[7];
#pragma unroll
        for (int i = 0; i < 7; ++i) {
            ixA[i] = curA[(i << 6) + gidx];
            ixB[i] = curB[(i << 6) + gidx];
        }

        // ---- 14 gathers (12 full + 2 tail-masked) ----
        uint4 ka[7], kb_[7];
#pragma unroll
        for (int i = 0; i < 6; ++i) {
            ka[i]  = *(const uint4*)(kp + (((uint32_t)ixA[i] << 6) | subs));
            kb_[i] = *(const uint4*)(kp + (((uint32_t)ixB[i] << 6) | subs));
        }
        ka[6] = make_uint4(0, 0, 0, 0);
        kb_[6] = make_uint4(0, 0, 0, 0);
        if (act6) {
            ka[6]  = *(const uint4*)(kp + (((uint32_t)ixA[6] << 6) | subs));
            kb_[6] = *(const uint4*)(kp + (((uint32_t)ixB[6] << 6) | subs));
        }

        // ---- latency cover: next-pair prefetch + target flags ----
        int pf0 = 0, pf1 = 0, pf2 = 0, pf3 = 0;
        uint4 bmn; int snA = 0, snB = 0;
        uint4 qnA, qnB;
        if (hasNext) {
            const int* ibn = inds + ((size_t)(rowA + 2 + half) << 10) + NLOC;
            pf0 = ibn[ht];
            pf1 = ibn[ht + 128];
            pf2 = ibn[ht + 256];
            if (ht < NRND - 384) pf3 = ibn[ht + 384];
            snA = seg32[rowA + 2];
            snB = seg32[rowA + 3];
            int sh = half ? snB : snA;
            bmn = ((const uint4*)(sbm + ((size_t)(sh & 63) << 9)))[ht];
            qnA = *(const uint4*)(q16 + ((size_t)(rowA + 2) << 6) + (sub << 4));
            qnB = *(const uint4*)(q16 + ((size_t)(rowA + 3) << 6) + (sub << 4));
        }
        int tfmA = 0, tfmB = 0;
        {
            int i0 = curA[(sub << 6) + gidx];
            if ((bm_lds[pp][0][i0 >> 5] >> (i0 & 31)) & 1u) tfmA |= 1;
            int i1 = curB[(sub << 6) + gidx];
            if ((bm_lds[pp][1][i1 >> 5] >> (i1 & 31)) & 1u) tfmB |= 1;
            if (sub < 3) {
                int j0 = curA[((sub + 4) << 6) + gidx];
                if (owned1 && ((bm_lds[pp][0][j0 >> 5] >> (j0 & 31)) & 1u)) tfmA |= 2;
                int j1 = curB[((sub + 4) << 6) + gidx];
                if (owned1 && ((bm_lds[pp][1][j1 >> 5] >> (j1 & 31)) & 1u)) tfmB |= 2;
            }
        }

        // ---- dots + quad reduce + owner capture + stores (both rows) ----
        const size_t obA = ((size_t)rowA << 10) + NLOC;
        const size_t obB = ((size_t)rowB << 10) + NLOC;
        float lgA0 = 0.f, lgA1 = 0.f, lgB0 = 0.f, lgB1 = 0.f;
#pragma unroll
        for (int it = 0; it < 7; ++it) {
            union { uint4 u; h2 h[4]; } kc;
            kc.u = ka[it];
            float aA = dot2(kc.h[0], qa0, 0.f);
            aA = dot2(kc.h[1], qa1, aA);
            aA = dot2(kc.h[2], qa2, aA);
            aA = dot2(kc.h[3], qa3, aA);
            kc.u = kb_[it];
            float aB = dot2(kc.h[0], qb0, 0.f);
            aB = dot2(kc.h[1], qb1, aB);
            aB = dot2(kc.h[2], qb2, aB);
            aB = dot2(kc.h[3], qb3, aB);
            aA = dpp_add<0xB1>(aA); aA = dpp_add<0x4E>(aA);
            aB = dpp_add<0xB1>(aB); aB = dpp_add<0x4E>(aB);
            if (sub == (it & 3)) {
                if (it < 4) { lgA0 = aA; lgB0 = aB; }
                else        { lgA1 = aA; lgB1 = aB; }
                if (it < 6 || act6) {
                    out[obA + (it << 6) + gidx] = aA;
                    out[obB + (it << 6) + gidx] = aB;
                }
            }
        }

        // ---- 6 parallel butterfly chains ----
        float z0 = __expf(lgA0) + (owned1 ? __expf(lgA1) : 0.f);
        float z1 = __expf(lgB0) + (owned1 ? __expf(lgB1) : 0.f);
        float c0 = (float)__popc((unsigned)tfmA);
        float c1 = (float)__popc((unsigned)tfmB);
        float s0 = ((tfmA & 1) ? lgA0 : 0.f) + ((tfmA & 2) ? lgA1 : 0.f);
        float s1 = ((tfmB & 1) ? lgB0 : 0.f) + ((tfmB & 2) ? lgB1 : 0.f);
#pragma unroll
        for (int off = 32; off >= 1; off >>= 1) {
            z0 += __shfl_xor(z0, off, 64);
            z1 += __shfl_xor(z1, off, 64);
            c0 += __shfl_xor(c0, off, 64);
            c1 += __shfl_xor(c1, off, 64);
            s0 += __shfl_xor(s0, off, 64);
            s1 += __shfl_xor(s1, off, 64);
        }
        if (lane == 0) {
            red[pp][0][w] = z0; red[pp][1][w] = c0; red[pp][2][w] = s0;
            red[pp][3][w] = z1; red[pp][4][w] = c1; red[pp][5][w] = s1;
        }

        // ---- commit prefetch into the other parity slots ----
        if (hasNext) {
            idx_lds[pp ^ 1][half][ht]       = pf0;
            idx_lds[pp ^ 1][half][ht + 128] = pf1;
            idx_lds[pp ^ 1][half][ht + 256] = pf2;
            if (ht < NRND - 384) idx_lds[pp ^ 1][half][ht + 384] = pf3;
            ((uint4*)bm_lds[pp ^ 1][half])[ht] = bmn;
            qcurA = qnA; qcurB = qnB;
            scurA = snA; scurB = snB;
        }
        __syncthreads();                   // ONE barrier per pair

        if (tid < 2) {
            const int  row  = rowA + tid;
            const int  sgn  = tid ? segB : segA;
            const int  base = tid * 3;
            if (sgn != 0) {
                const float Z  = zp[2*t + tid] +
                    (red[pp][base][0] + red[pp][base][1]) + (red[pp][base][2] + red[pp][base][3]);
                const float T  = tp[2*t + tid] +
                    (red[pp][base+1][0] + red[pp][base+1][1]) + (red[pp][base+1][2] + red[pp][base+1][3]);
                const float SL = sp[2*t + tid] +
                    (red[pp][base+2][0] + red[pp][base+2][1]) + (red[pp][base+2][2] + red[pp][base+2][3]);
                // closed-form KL; T >= 1 (center sample matches itself)
                ws_kl[row] = -__logf(T) - SL / T + __logf(Z);
            } else {
                ws_kl[row] = 0.f;
            }
        }
    }
}

// ---------------------------------------------------------------------------
// Fallback (generic shapes / tiny ws): per-thread gather from native layout.
// ---------------------------------------------------------------------------
__global__ __launch_bounds__(256)
void affinity_fallback(const float* __restrict__ key_f,
                       const float* __restrict__ query_f,
                       const int*   __restrict__ seg32,
                       const int*   __restrict__ inds,
                       float* __restrict__ out,
                       float* __restrict__ ws_kl,
                       int N, int S, float scale)
{
    const int bid = blockIdx.x;
    const int tid = threadIdx.x;
    const int b   = bid / N;

    __shared__ float q_lds[CDIM];
    __shared__ float redA[4], redB[4], redC[4];

    if (tid < CDIM) {
        int n = bid - b * N;
        q_lds[tid] = query_f[((size_t)(b * CDIM + tid)) * N + n];
    }
    const int seg_n = seg32[bid];
    __syncthreads();

    float q[CDIM];
#pragma unroll
    for (int c = 0; c < CDIM; ++c) q[c] = q_lds[c];

    const size_t rowbase = (size_t)bid * S;
    const int4 iv = ((const int4*)(inds + rowbase))[tid];
    const int idxv[4] = {iv.x, iv.y, iv.z, iv.w};

    float lg[4];
    int   tf[4];
#pragma unroll
    for (int k = 0; k < 4; ++k) {
        int idx = idxv[k];
        tf[k] = (seg32[b * N + idx] == seg_n) ? 1 : 0;
        float acc = 0.f;
#pragma unroll
        for (int c = 0; c < CDIM; ++c)
            acc = fmaf(key_f[((size_t)(b * CDIM + c)) * N + idx], q[c], acc);
        lg[k] = acc * scale;
    }
    ((float4*)(out + rowbase))[tid] = make_float4(lg[0], lg[1], lg[2], lg[3]);

    const int lane = tid & 63, wv = tid >> 6;
    float m = fmaxf(fmaxf(lg[0], lg[1]), fmaxf(lg[2], lg[3]));
#pragma unroll
    for (int off = 32; off >= 1; off >>= 1)
        m = fmaxf(m, __shfl_xor(m, off, 64));
    if (lane == 0) redA[wv] = m;
    __syncthreads();
    m = fmaxf(fmaxf(redA[0], redA[1]), fmaxf(redA[2], redA[3]));

    float e[4], z = 0.f, tcnt = 0.f;
#pragma unroll
    for (int k = 0; k < 4; ++k) {
        e[k] = expf(lg[k] - m);
        z += e[k];
        tcnt += (float)tf[k];
    }
#pragma unroll
    for (int off = 32; off >= 1; off >>= 1) {
        z    += __shfl_xor(z, off, 64);
        tcnt += __shfl_xor(tcnt, off, 64);
    }
    if (lane == 0) { redB[wv] = z; redC[wv] = tcnt; }
    __syncthreads();
    const float Z = redB[0] + redB[1] + redB[2] + redB[3];
    const float T = redC[0] + redC[1] + redC[2] + redC[3];

    float kl = 0.f;
    if (seg_n != 0) {
        const float invZ = 1.f / (Z + 1e-9f);
        const float invT = 1.f / (T + 1e-9f);
        const float nlT  = -logf(T + 1e-9f);
#pragma unroll
        for (int k = 0; k < 4; ++k) {
            if (tf[k]) {
                float p = e[k] * invZ;
                float yp = logf(fmaxf(p, 1e-8f));
                kl += invT * (nlT - yp);
            }
        }
    }
#pragma unroll
    for (int off = 32; off >= 1; off >>= 1)
        kl += __shfl_xor(kl, off, 64);
    if (lane == 0) redA[wv] = kl;
    __syncthreads();
    if (tid == 0)
        ws_kl[bid] = redA[0] + redA[1] + redA[2] + redA[3];
}

// ---------------------------------------------------------------------------
// Kernel 3: deterministic single-block loss reduction (1024 threads).
// ---------------------------------------------------------------------------
__global__ __launch_bounds__(1024)
void loss_reduce(const float* __restrict__ ws_kl,
                 const int* __restrict__ seg32,
                 float* __restrict__ out_loss, int rows)
{
    const int tid = threadIdx.x;
    float s = 0.f, c = 0.f;
    for (int i = tid; i < rows; i += 1024) {
        s += ws_kl[i];
        c += (seg32[i] != 0) ? 1.f : 0.f;
    }
#pragma unroll
    for (int off = 32; off >= 1; off >>= 1) {
        s += __shfl_xor(s, off, 64);
        c += __shfl_xor(c, off, 64);
    }
    __shared__ float sA[16], sB[16];
    const int lane = tid & 63, wv = tid >> 6;
    if (lane == 0) { sA[wv] = s; sB[wv] = c; }
    __syncthreads();
    if (tid == 0) {
        float ts = 0.f, tc = 0.f;
#pragma unroll
        for (int k = 0; k < 16; ++k) { ts += sA[k]; tc += sB[k]; }
        out_loss[0] = ts / (tc + 1e-9f);
    }
}

// ---------------------------------------------------------------------------
extern "C" void kernel_launch(void* const* d_in, const int* in_sizes, int n_in,
                              void* d_out, int out_size, void* d_ws, size_t ws_size,
                              hipStream_t stream)
{
    const float* key_f   = (const float*)d_in[0];
    const float* query_f = (const float*)d_in[1];
    const int*   seg32   = (const int*)d_in[2];
    const int*   inds    = (const int*)d_in[3];
    float* out = (float*)d_out;

    const int N    = NPIX;
    const int rows = in_sizes[2];            // B*N
    const int S    = in_sizes[3] / rows;     // 1024
    const float scale = (float)(1.0 / sqrt((double)CDIM));
    const int B    = rows / N;

    // ws: key16 | q16 | seg8 | segbit | zA | tA | slA | kl
    const size_t off_q16 = (size_t)rows * 64;
    const size_t off_s8  = off_q16 + (size_t)rows * 64;
    const size_t off_sb  = (off_s8 + (size_t)rows + 255) & ~(size_t)255;
    const size_t sb_words = (size_t)B * 64 * 512;     // == 2*rows
    const size_t off_zA  = (off_sb + sb_words * 4 + 255) & ~(size_t)255;
    const size_t off_tA  = off_zA + (size_t)rows * 4;
    const size_t off_slA = off_tA + (size_t)rows * 4;
    const size_t off_kl  = off_slA + (size_t)rows * 4;
    const size_t need    = off_kl + (size_t)rows * 4;

    uint8_t* wsb = (uint8_t*)d_ws;
    const bool geom_ok = (S == SSAM) && (rows % N == 0) &&
                         (rows % ROWS_PER_BLOCK == 0);

    if (ws_size >= need && geom_ok) {
        uint8_t*  key16  = wsb;
        uint8_t*  q16    = wsb + off_q16;
        uint8_t*  seg8   = wsb + off_s8;
        uint32_t* segbit = (uint32_t*)(wsb + off_sb);
        float*    zA     = (float*)(wsb + off_zA);
        float*    tA     = (float*)(wsb + off_tA);
        float*    slA    = (float*)(wsb + off_slA);
        float*    wskl   = (float*)(wsb + off_kl);

        prep_kernel<<<(rows + 255) / 256, 256, 0, stream>>>(
            key_f, query_f, seg32, key16, q16, seg8, segbit, N, rows, scale);
        segbit_build<<<(rows + 255) / 256, 256, 0, stream>>>(
            seg32, segbit, N, rows);
        dense_local<<<B * 256, 256, 0, stream>>>(
            key16, q16, seg8, out, zA, tA, slA);
        affinity_rand<<<rows / ROWS_PER_BLOCK, 256, 0, stream>>>(
            inds, key16, q16, seg32, segbit, zA, tA, slA, out, wskl);
        loss_reduce<<<1, 1024, 0, stream>>>(wskl, seg32, out + (size_t)rows * S, rows);
    } else {
        float* wskl = (float*)d_ws;
        affinity_fallback<<<rows, 256, 0, stream>>>(
            key_f, query_f, seg32, inds, out, wskl, N, S, scale);
        loss_reduce<<<1, 1024, 0, stream>>>(wskl, seg32, out + (size_t)rows * S, rows);
    }
}